// Round 1
// baseline (238.179 us; speedup 1.0000x reference)
//
#include <hip/hip_runtime.h>
#include <hip/hip_bf16.h>
#include <cstdint>
#include <cstddef>

#define DDIM 1024
#define NHEADS 16
#define HDIM 64
#define NSEQ 2048
#define NTOK 4096

typedef float f32x4 __attribute__((ext_vector_type(4)));
typedef __bf16 bf16x8 __attribute__((ext_vector_type(8)));
typedef unsigned short u16x8 __attribute__((ext_vector_type(8)));

typedef __attribute__((address_space(1))) const unsigned int gq_t;
typedef __attribute__((address_space(3))) unsigned int lq_t;

__device__ __forceinline__ unsigned short f2bf(float f) {
    union { float f; unsigned int u; } v; v.f = f;
    unsigned int u = v.u;
    u += 0x7FFFu + ((u >> 16) & 1u);
    return (unsigned short)(u >> 16);
}

// ---------------- fp32 -> bf16 convert ----------------
__global__ __launch_bounds__(256) void cvt_kernel(const float* __restrict__ src,
                                                  unsigned short* __restrict__ dst,
                                                  int n8) {
    int i = blockIdx.x * 256 + threadIdx.x;
    if (i >= n8) return;
    const float4* s4 = (const float4*)src + (size_t)i * 2;
    float4 a = s4[0], b = s4[1];
    unsigned short o[8] __attribute__((aligned(16)));
    o[0] = f2bf(a.x); o[1] = f2bf(a.y); o[2] = f2bf(a.z); o[3] = f2bf(a.w);
    o[4] = f2bf(b.x); o[5] = f2bf(b.y); o[6] = f2bf(b.z); o[7] = f2bf(b.w);
    *(u16x8*)(dst + (size_t)i * 8) = *(const u16x8*)o;
}

// ---------------- GEMM: C[m,n] = sum_k A[m,k]*W[n,k] + bias[n] ----------------
// A: [4096][1024] bf16, W: [1024][1024] bf16, C: [4096][1024] (bf16 or f32)
// 128x128 tile, BK=32, 256 threads (4 waves, 2x2 wave grid, 64x64 per wave)
template <bool OUTF32>
__device__ __forceinline__ void gemm_body(const unsigned short* __restrict__ A,
                                          const unsigned short* __restrict__ W,
                                          const float* __restrict__ bias,
                                          void* __restrict__ Cout) {
    __shared__ unsigned short As[128 * 32];
    __shared__ unsigned short Bs[128 * 32];
    const int tid = threadIdx.x, lane = tid & 63, wid = tid >> 6;
    const int r = lane & 15, g = lane >> 4;
    const int mbase = blockIdx.y * 128;
    const int nbase = blockIdx.x * 128;
    const int wm = (wid >> 1) * 64, wn = (wid & 1) * 64;

    f32x4 zero = {0.f, 0.f, 0.f, 0.f};
    f32x4 acc[4][4];
#pragma unroll
    for (int mi = 0; mi < 4; ++mi)
#pragma unroll
        for (int ni = 0; ni < 4; ++ni) acc[mi][ni] = zero;

    for (int kt = 0; kt < 1024; kt += 32) {
        __syncthreads();
#pragma unroll
        for (int j = 0; j < 2; ++j) {
            int ub = wid * 64 + j * 256;  // wave-uniform 16B-unit base
            int uu = ub + lane;
            const unsigned short* ga =
                A + (size_t)(mbase + (uu >> 2)) * 1024 + kt + (uu & 3) * 8;
            __builtin_amdgcn_global_load_lds((gq_t*)ga, (lq_t*)(As + ub * 8), 16, 0, 0);
            const unsigned short* gb =
                W + (size_t)(nbase + (uu >> 2)) * 1024 + kt + (uu & 3) * 8;
            __builtin_amdgcn_global_load_lds((gq_t*)gb, (lq_t*)(Bs + ub * 8), 16, 0, 0);
        }
        __syncthreads();
        bf16x8 af[4], bf[4];
#pragma unroll
        for (int mi = 0; mi < 4; ++mi)
            af[mi] = *(const bf16x8*)(As + (wm + mi * 16 + r) * 32 + g * 8);
#pragma unroll
        for (int ni = 0; ni < 4; ++ni)
            bf[ni] = *(const bf16x8*)(Bs + (wn + ni * 16 + r) * 32 + g * 8);
#pragma unroll
        for (int mi = 0; mi < 4; ++mi)
#pragma unroll
            for (int ni = 0; ni < 4; ++ni)
                acc[mi][ni] = __builtin_amdgcn_mfma_f32_16x16x32_bf16(
                    af[mi], bf[ni], acc[mi][ni], 0, 0, 0);
    }
    // epilogue: C row = (lane>>4)*4 + reg, col = lane&15
#pragma unroll
    for (int mi = 0; mi < 4; ++mi) {
#pragma unroll
        for (int ni = 0; ni < 4; ++ni) {
            int col = nbase + wn + ni * 16 + r;
            float bv = bias[col];
#pragma unroll
            for (int rr = 0; rr < 4; ++rr) {
                int row = mbase + wm + mi * 16 + g * 4 + rr;
                float val = acc[mi][ni][rr] + bv;
                if (OUTF32)
                    ((float*)Cout)[(size_t)row * 1024 + col] = val;
                else
                    ((unsigned short*)Cout)[(size_t)row * 1024 + col] = f2bf(val);
            }
        }
    }
}

__global__ __launch_bounds__(256) void gemm_qkv_kernel(
    const unsigned short* __restrict__ qb, const unsigned short* __restrict__ kb,
    const unsigned short* __restrict__ vb, const unsigned short* __restrict__ Wq,
    const unsigned short* __restrict__ Wk, const unsigned short* __restrict__ Wv,
    const float* __restrict__ bq, const float* __restrict__ bk,
    const float* __restrict__ bv, unsigned short* __restrict__ Qp,
    unsigned short* __restrict__ Kp, unsigned short* __restrict__ Vp) {
    int z = blockIdx.z;
    const unsigned short* A = (z == 0) ? qb : (z == 1) ? kb : vb;
    const unsigned short* W = (z == 0) ? Wq : (z == 1) ? Wk : Wv;
    const float* bias = (z == 0) ? bq : (z == 1) ? bk : bv;
    unsigned short* C = (z == 0) ? Qp : (z == 1) ? Kp : Vp;
    gemm_body<false>(A, W, bias, C);
}

__global__ __launch_bounds__(256) void gemm_out_kernel(
    const unsigned short* __restrict__ AO, const unsigned short* __restrict__ Wo,
    const float* __restrict__ bo, float* __restrict__ out) {
    gemm_body<true>(AO, Wo, bo, out);
}

// ---------------- flash attention ----------------
// grid: (qt=32, bh=32), 256 threads = 4 waves, each wave owns 16 q-rows.
// QBLK=64, KVBLK=64, d=64.
__global__ __launch_bounds__(256) void attn_kernel(
    const unsigned short* __restrict__ Qp, const unsigned short* __restrict__ Kp,
    const unsigned short* __restrict__ Vp, unsigned short* __restrict__ AO) {
    __shared__ unsigned short Ks[64 * 64];      // K tile, linear (global_load_lds)
    __shared__ unsigned short Vt[64 * 72];      // V^T tile, padded rows
    __shared__ unsigned short Pb[4][16 * 72];   // per-wave P tile, padded rows

    const int tid = threadIdx.x, lane = tid & 63, wid = tid >> 6;
    const int r = lane & 15, g = lane >> 4;
    const int qt = blockIdx.x, bh = blockIdx.y;
    const int b = bh >> 4, h = bh & 15;
    const size_t hoff = (size_t)h * HDIM;

    // Q fragments (A-operand): row = lane&15, k = (lane>>4)*8 + e
    bf16x8 qf[2];
    {
        int qrow = b * NSEQ + qt * 64 + wid * 16 + r;
        const unsigned short* qp = Qp + (size_t)qrow * DDIM + hoff + g * 8;
        qf[0] = *(const bf16x8*)(qp);
        qf[1] = *(const bf16x8*)(qp + 32);
    }

    f32x4 zero = {0.f, 0.f, 0.f, 0.f};
    float mrow[4], lrow[4];
    f32x4 oacc[4];
#pragma unroll
    for (int i = 0; i < 4; ++i) {
        mrow[i] = -3.0e38f;
        lrow[i] = 0.f;
        oacc[i] = zero;
    }

    const int vkv = tid >> 2, vd0 = (tid & 3) * 16;
    const unsigned short* Vbase = Vp + (size_t)(b * NSEQ) * DDIM + hoff;
    unsigned short* Pw = &Pb[wid][0];

    for (int kv0 = 0; kv0 < NSEQ; kv0 += 64) {
        // V tile to registers (global reads can precede barrier)
        const unsigned short* vp = Vbase + (size_t)(kv0 + vkv) * DDIM + vd0;
        u16x8 v0 = *(const u16x8*)(vp);
        u16x8 v1 = *(const u16x8*)(vp + 8);

        __syncthreads();  // all waves done with previous Ks/Vt

        // K staging: linear [64][64]
#pragma unroll
        for (int j = 0; j < 2; ++j) {
            int ub = wid * 64 + j * 256;
            int uu = ub + lane;
            const unsigned short* gk =
                Kp + (size_t)(b * NSEQ + kv0 + (uu >> 3)) * DDIM + hoff + (uu & 7) * 8;
            __builtin_amdgcn_global_load_lds((gq_t*)gk, (lq_t*)(Ks + ub * 8), 16, 0, 0);
        }
        // V transpose into Vt[d][kv]
#pragma unroll
        for (int e = 0; e < 8; ++e) {
            Vt[(vd0 + e) * 72 + vkv] = v0[e];
            Vt[(vd0 + 8 + e) * 72 + vkv] = v1[e];
        }
        __syncthreads();  // staging complete (drains vmcnt + lgkm)

        // S = (Q K^T) * scale ; S row = g*4+rr, col = nf*16 + r
        f32x4 s[4];
#pragma unroll
        for (int nf = 0; nf < 4; ++nf) {
            f32x4 a = zero;
            a = __builtin_amdgcn_mfma_f32_16x16x32_bf16(
                qf[0], *(const bf16x8*)(Ks + (nf * 16 + r) * 64 + g * 8), a, 0, 0, 0);
            a = __builtin_amdgcn_mfma_f32_16x16x32_bf16(
                qf[1], *(const bf16x8*)(Ks + (nf * 16 + r) * 64 + 32 + g * 8), a, 0, 0, 0);
            s[nf] = a * 0.125f;
        }
        // row max over 64 cols (reduce over the 16 lanes of this group)
        float pm[4];
#pragma unroll
        for (int rr = 0; rr < 4; ++rr)
            pm[rr] = fmaxf(fmaxf(s[0][rr], s[1][rr]), fmaxf(s[2][rr], s[3][rr]));
#pragma unroll
        for (int msk = 1; msk <= 8; msk <<= 1)
#pragma unroll
            for (int rr = 0; rr < 4; ++rr)
                pm[rr] = fmaxf(pm[rr], __shfl_xor(pm[rr], msk, 64));

        float al[4];
#pragma unroll
        for (int rr = 0; rr < 4; ++rr) {
            float mn = fmaxf(mrow[rr], pm[rr]);
            al[rr] = __expf(mrow[rr] - mn);
            mrow[rr] = mn;
        }
        float rs[4] = {0.f, 0.f, 0.f, 0.f};
#pragma unroll
        for (int nf = 0; nf < 4; ++nf)
#pragma unroll
            for (int rr = 0; rr < 4; ++rr) {
                float p = __expf(s[nf][rr] - mrow[rr]);
                s[nf][rr] = p;
                rs[rr] += p;
            }
#pragma unroll
        for (int msk = 1; msk <= 8; msk <<= 1)
#pragma unroll
            for (int rr = 0; rr < 4; ++rr) rs[rr] += __shfl_xor(rs[rr], msk, 64);
#pragma unroll
        for (int rr = 0; rr < 4; ++rr) lrow[rr] = lrow[rr] * al[rr] + rs[rr];
#pragma unroll
        for (int df = 0; df < 4; ++df)
#pragma unroll
            for (int rr = 0; rr < 4; ++rr) oacc[df][rr] *= al[rr];

        // P (C-layout) -> per-wave LDS -> A-layout fragments
#pragma unroll
        for (int nf = 0; nf < 4; ++nf)
#pragma unroll
            for (int rr = 0; rr < 4; ++rr)
                Pw[(g * 4 + rr) * 72 + nf * 16 + r] = f2bf(s[nf][rr]);

        bf16x8 pa0 = *(const bf16x8*)(Pw + r * 72 + g * 8);
        bf16x8 pa1 = *(const bf16x8*)(Pw + r * 72 + 32 + g * 8);
#pragma unroll
        for (int df = 0; df < 4; ++df) {
            oacc[df] = __builtin_amdgcn_mfma_f32_16x16x32_bf16(
                pa0, *(const bf16x8*)(Vt + (df * 16 + r) * 72 + g * 8), oacc[df], 0, 0, 0);
            oacc[df] = __builtin_amdgcn_mfma_f32_16x16x32_bf16(
                pa1, *(const bf16x8*)(Vt + (df * 16 + r) * 72 + 32 + g * 8), oacc[df], 0, 0, 0);
        }
    }

    // epilogue
    int row = b * NSEQ + qt * 64 + wid * 16 + g * 4;
#pragma unroll
    for (int df = 0; df < 4; ++df)
#pragma unroll
        for (int rr = 0; rr < 4; ++rr) {
            float o = oacc[df][rr] / lrow[rr];
            AO[(size_t)(row + rr) * DDIM + hoff + df * 16 + r] = f2bf(o);
        }
}

// ---------------- host launch ----------------
extern "C" void kernel_launch(void* const* d_in, const int* in_sizes, int n_in,
                              void* d_out, int out_size, void* d_ws, size_t ws_size,
                              hipStream_t stream) {
    const float* q = (const float*)d_in[0];
    const float* k = (const float*)d_in[1];
    const float* v = (const float*)d_in[2];
    const float* Wq = (const float*)d_in[3];
    const float* bq = (const float*)d_in[4];
    const float* Wk = (const float*)d_in[5];
    const float* bk = (const float*)d_in[6];
    const float* Wv = (const float*)d_in[7];
    const float* bv = (const float*)d_in[8];
    const float* Wo = (const float*)d_in[9];
    const float* bo = (const float*)d_in[10];
    float* out = (float*)d_out;

    unsigned short* ws = (unsigned short*)d_ws;
    const size_t TOKD = (size_t)NTOK * DDIM;  // 4,194,304
    const size_t WD = (size_t)DDIM * DDIM;    // 1,048,576
    unsigned short* qb = ws;
    unsigned short* kb = qb + TOKD;
    unsigned short* vb = kb + TOKD;
    unsigned short* Wqb = vb + TOKD;
    unsigned short* Wkb = Wqb + WD;
    unsigned short* Wvb = Wkb + WD;
    unsigned short* Wob = Wvb + WD;
    unsigned short* Qp = Wob + WD;
    unsigned short* Kp = Qp + TOKD;
    unsigned short* Vp = Kp + TOKD;
    unsigned short* AOp = Vp + TOKD;
    // total: 7*TOKD + 4*WD elements * 2B = ~64 MB

    const int tok8 = (int)(TOKD / 8);  // 524288 -> 2048 blocks
    const int w8 = (int)(WD / 8);      // 131072 -> 512 blocks
    cvt_kernel<<<dim3(tok8 / 256), 256, 0, stream>>>(q, qb, tok8);
    cvt_kernel<<<dim3(tok8 / 256), 256, 0, stream>>>(k, kb, tok8);
    cvt_kernel<<<dim3(tok8 / 256), 256, 0, stream>>>(v, vb, tok8);
    cvt_kernel<<<dim3(w8 / 256), 256, 0, stream>>>(Wq, Wqb, w8);
    cvt_kernel<<<dim3(w8 / 256), 256, 0, stream>>>(Wk, Wkb, w8);
    cvt_kernel<<<dim3(w8 / 256), 256, 0, stream>>>(Wv, Wvb, w8);
    cvt_kernel<<<dim3(w8 / 256), 256, 0, stream>>>(Wo, Wob, w8);

    gemm_qkv_kernel<<<dim3(8, 32, 3), 256, 0, stream>>>(qb, kb, vb, Wqb, Wkb, Wvb,
                                                        bq, bk, bv, Qp, Kp, Vp);
    attn_kernel<<<dim3(32, 32), 256, 0, stream>>>(Qp, Kp, Vp, AOp);
    gemm_out_kernel<<<dim3(8, 32), 256, 0, stream>>>(AOp, Wob, bo, out);
}

// Round 2
// 170.948 us; speedup vs baseline: 1.3933x; 1.3933x over previous
//
#include <hip/hip_runtime.h>
#include <hip/hip_bf16.h>
#include <cstdint>
#include <cstddef>

#define DDIM 1024
#define NHEADS 16
#define HDIM 64
#define NSEQ 2048
#define NTOK 4096
#define QSCALE 0.18033688011112042f  // 0.125 * log2(e): folded into Q projection

typedef float f32x4 __attribute__((ext_vector_type(4)));
typedef __bf16 bf16x8 __attribute__((ext_vector_type(8)));
typedef unsigned short u16x8 __attribute__((ext_vector_type(8)));

typedef __attribute__((address_space(1))) const unsigned int gq_t;
typedef __attribute__((address_space(3))) unsigned int lq_t;

__device__ __forceinline__ unsigned short f2bf(float f) {
    union { float f; unsigned int u; } v; v.f = f;
    unsigned int u = v.u;
    u += 0x7FFFu + ((u >> 16) & 1u);
    return (unsigned short)(u >> 16);
}

// raw v_exp_f32 = 2^x ; s_nop covers the trans-op hazard for the consumer
__device__ __forceinline__ float exp2_fast(float x) {
    float r;
    asm("v_exp_f32 %0, %1\n\ts_nop 0" : "=v"(r) : "v"(x));
    return r;
}

// ---------------- fp32 -> bf16 converts (fused, 2 launches) ----------------
__global__ __launch_bounds__(256) void cvt3_kernel(
    const float* __restrict__ a0, const float* __restrict__ a1,
    const float* __restrict__ a2, unsigned short* __restrict__ d0,
    unsigned short* __restrict__ d1, unsigned short* __restrict__ d2) {
    int z = blockIdx.z;
    const float* s = z == 0 ? a0 : z == 1 ? a1 : a2;
    unsigned short* d = z == 0 ? d0 : z == 1 ? d1 : d2;
    int i = blockIdx.x * 256 + threadIdx.x;
    const float4* s4 = (const float4*)s + (size_t)i * 2;
    float4 a = s4[0], b = s4[1];
    unsigned short o[8] __attribute__((aligned(16)));
    o[0] = f2bf(a.x); o[1] = f2bf(a.y); o[2] = f2bf(a.z); o[3] = f2bf(a.w);
    o[4] = f2bf(b.x); o[5] = f2bf(b.y); o[6] = f2bf(b.z); o[7] = f2bf(b.w);
    *(u16x8*)(d + (size_t)i * 8) = *(const u16x8*)o;
}

__global__ __launch_bounds__(256) void cvt4_kernel(
    const float* __restrict__ a0, const float* __restrict__ a1,
    const float* __restrict__ a2, const float* __restrict__ a3,
    unsigned short* __restrict__ d0, unsigned short* __restrict__ d1,
    unsigned short* __restrict__ d2, unsigned short* __restrict__ d3) {
    int z = blockIdx.z;
    const float* s = z == 0 ? a0 : z == 1 ? a1 : z == 2 ? a2 : a3;
    unsigned short* d = z == 0 ? d0 : z == 1 ? d1 : z == 2 ? d2 : d3;
    int i = blockIdx.x * 256 + threadIdx.x;
    const float4* s4 = (const float4*)s + (size_t)i * 2;
    float4 a = s4[0], b = s4[1];
    unsigned short o[8] __attribute__((aligned(16)));
    o[0] = f2bf(a.x); o[1] = f2bf(a.y); o[2] = f2bf(a.z); o[3] = f2bf(a.w);
    o[4] = f2bf(b.x); o[5] = f2bf(b.y); o[6] = f2bf(b.z); o[7] = f2bf(b.w);
    *(u16x8*)(d + (size_t)i * 8) = *(const u16x8*)o;
}

// ---------------- GEMM: C[m,n] = sum_k A[m,k]*W[n,k] + bias[n] ----------------
// mode 0: Q  -> bf16 token-major, scaled by QSCALE
// mode 1: K  -> bf16 head-major [32][2048][64]
// mode 2: V  -> bf16 token-major
// mode 3: O  -> f32 token-major (final output)
__device__ __forceinline__ void gemm_body(const unsigned short* __restrict__ A,
                                          const unsigned short* __restrict__ W,
                                          const float* __restrict__ bias,
                                          int mode, void* __restrict__ Cout) {
    __shared__ __align__(16) unsigned short As[128 * 32];
    __shared__ __align__(16) unsigned short Bs[128 * 32];
    const int tid = threadIdx.x, lane = tid & 63, wid = tid >> 6;
    const int r = lane & 15, g = lane >> 4;
    const int mbase = blockIdx.y * 128;
    const int nbase = blockIdx.x * 128;
    const int wm = (wid >> 1) * 64, wn = (wid & 1) * 64;

    f32x4 zero = {0.f, 0.f, 0.f, 0.f};
    f32x4 acc[4][4];
#pragma unroll
    for (int mi = 0; mi < 4; ++mi)
#pragma unroll
        for (int ni = 0; ni < 4; ++ni) acc[mi][ni] = zero;

    for (int kt = 0; kt < 1024; kt += 32) {
        __syncthreads();
#pragma unroll
        for (int j = 0; j < 2; ++j) {
            int ub = wid * 64 + j * 256;  // wave-uniform 16B-unit base
            int uu = ub + lane;
            const unsigned short* ga =
                A + (size_t)(mbase + (uu >> 2)) * 1024 + kt + (uu & 3) * 8;
            __builtin_amdgcn_global_load_lds((gq_t*)ga, (lq_t*)(As + ub * 8), 16, 0, 0);
            const unsigned short* gb =
                W + (size_t)(nbase + (uu >> 2)) * 1024 + kt + (uu & 3) * 8;
            __builtin_amdgcn_global_load_lds((gq_t*)gb, (lq_t*)(Bs + ub * 8), 16, 0, 0);
        }
        __syncthreads();
        bf16x8 af[4], bf[4];
#pragma unroll
        for (int mi = 0; mi < 4; ++mi)
            af[mi] = *(const bf16x8*)(As + (wm + mi * 16 + r) * 32 + g * 8);
#pragma unroll
        for (int ni = 0; ni < 4; ++ni)
            bf[ni] = *(const bf16x8*)(Bs + (wn + ni * 16 + r) * 32 + g * 8);
#pragma unroll
        for (int mi = 0; mi < 4; ++mi)
#pragma unroll
            for (int ni = 0; ni < 4; ++ni)
                acc[mi][ni] = __builtin_amdgcn_mfma_f32_16x16x32_bf16(
                    af[mi], bf[ni], acc[mi][ni], 0, 0, 0);
    }
    // epilogue: C row = (lane>>4)*4 + reg, col = lane&15
#pragma unroll
    for (int mi = 0; mi < 4; ++mi) {
#pragma unroll
        for (int ni = 0; ni < 4; ++ni) {
            int c = nbase + wn + ni * 16 + r;
            float bv = bias[c];
#pragma unroll
            for (int rr = 0; rr < 4; ++rr) {
                int m = mbase + wm + mi * 16 + g * 4 + rr;
                float val = acc[mi][ni][rr] + bv;
                if (mode == 0) {
                    ((unsigned short*)Cout)[(size_t)m * 1024 + c] = f2bf(val * QSCALE);
                } else if (mode == 1) {
                    size_t addr = ((size_t)((m >> 11) * 16 + (c >> 6)) * 2048 +
                                   (size_t)(m & 2047)) * 64 + (c & 63);
                    ((unsigned short*)Cout)[addr] = f2bf(val);
                } else if (mode == 2) {
                    ((unsigned short*)Cout)[(size_t)m * 1024 + c] = f2bf(val);
                } else {
                    ((float*)Cout)[(size_t)m * 1024 + c] = val;
                }
            }
        }
    }
}

__global__ __launch_bounds__(256) void gemm_qkv_kernel(
    const unsigned short* __restrict__ qb, const unsigned short* __restrict__ kb,
    const unsigned short* __restrict__ vb, const unsigned short* __restrict__ Wq,
    const unsigned short* __restrict__ Wk, const unsigned short* __restrict__ Wv,
    const float* __restrict__ bq, const float* __restrict__ bk,
    const float* __restrict__ bv, unsigned short* __restrict__ Qp,
    unsigned short* __restrict__ Kp, unsigned short* __restrict__ Vp) {
    int z = blockIdx.z;
    const unsigned short* A = (z == 0) ? qb : (z == 1) ? kb : vb;
    const unsigned short* W = (z == 0) ? Wq : (z == 1) ? Wk : Wv;
    const float* bias = (z == 0) ? bq : (z == 1) ? bk : bv;
    unsigned short* C = (z == 0) ? Qp : (z == 1) ? Kp : Vp;
    gemm_body(A, W, bias, z, C);
}

__global__ __launch_bounds__(256) void gemm_out_kernel(
    const unsigned short* __restrict__ AO, const unsigned short* __restrict__ Wo,
    const float* __restrict__ bo, float* __restrict__ out) {
    gemm_body(AO, Wo, bo, 3, out);
}

// ---------------- V transpose: [4096 tok][1024] -> [32 bh][64 d][2048 n] ----
__global__ __launch_bounds__(256) void vtrans_kernel(
    const unsigned short* __restrict__ Vp, unsigned short* __restrict__ Vt) {
    __shared__ __align__(16) unsigned short T[64 * 80];
    const int tid = threadIdx.x;
    const int n0 = blockIdx.x * 64, bh = blockIdx.y;
    const int b = bh >> 4, h = bh & 15;
    const unsigned short* src = Vp + (size_t)(b * NSEQ + n0) * DDIM + h * HDIM;
#pragma unroll
    for (int j = 0; j < 2; ++j) {
        int idx = j * 256 + tid;
        int n = idx >> 3, c = (idx & 7) * 8;
        u16x8 val = *(const u16x8*)(src + (size_t)n * DDIM + c);
        *(u16x8*)(&T[n * 80 + c]) = val;
    }
    __syncthreads();
    unsigned short* dst = Vt + (size_t)bh * HDIM * NSEQ + n0;
#pragma unroll
    for (int j = 0; j < 2; ++j) {
        int idx = j * 256 + tid;
        int d = idx >> 3, nn = (idx & 7) * 8, rot = idx & 7;
        unsigned short o[8] __attribute__((aligned(16)));
#pragma unroll
        for (int e0 = 0; e0 < 8; ++e0) {
            int e = (e0 + rot) & 7;  // stagger lanes across banks (4-way not 16-way)
            o[e] = T[(nn + e) * 80 + d];
        }
        *(u16x8*)(dst + (size_t)d * NSEQ + nn) = *(const u16x8*)o;
    }
}

// ---------------- flash attention ----------------
// grid (16 qt, 32 bh), 512 threads = 8 waves, wave owns 16 q-rows (QBLK=128).
// K head-major [bh][2048][64]; V^T head-major [bh][64][2048].
// K/V tiles [64][64] bf16, double-buffered, XOR-swizzled via pre-swizzled
// global source (global_load_lds dest must stay linear).
__global__ __launch_bounds__(512, 4) void attn_kernel(
    const unsigned short* __restrict__ Qp,   // [4096][1024], pre-scaled by QSCALE
    const unsigned short* __restrict__ Kh,   // [32][2048][64]
    const unsigned short* __restrict__ Vt,   // [32][64][2048]
    unsigned short* __restrict__ AO) {       // [4096][1024]
    __shared__ __align__(16) unsigned short Ks[2][64 * 64];
    __shared__ __align__(16) unsigned short Vs[2][64 * 64];
    __shared__ __align__(16) unsigned short Pb[8][16 * 72];

    const int tid = threadIdx.x, lane = tid & 63, wid = tid >> 6;
    const int r = lane & 15, g = lane >> 4;
    const int qt = blockIdx.x, bh = blockIdx.y;
    const int b = bh >> 4, h = bh & 15;

    // Q fragments (A-operand): row = lane&15, k = (lane>>4)*8 + e
    bf16x8 qf[2];
    {
        int qrow = b * NSEQ + qt * 128 + wid * 16 + r;
        const unsigned short* qp = Qp + (size_t)qrow * DDIM + h * HDIM + g * 8;
        qf[0] = *(const bf16x8*)(qp);
        qf[1] = *(const bf16x8*)(qp + 32);
    }

    const unsigned short* Kt = Kh + (size_t)bh * NSEQ * HDIM;
    const unsigned short* Vb = Vt + (size_t)bh * HDIM * NSEQ;
    unsigned short* Pw = &Pb[wid][0];

    const f32x4 zero = {0.f, 0.f, 0.f, 0.f};
    f32x4 oacc[4];
    f32x4 lacc = zero;
    float mrow[4];
#pragma unroll
    for (int i = 0; i < 4; ++i) { mrow[i] = -3.0e38f; oacc[i] = zero; }

    bf16x8 ones;
    {
        union { u16x8 u; bf16x8 b; } cv;
#pragma unroll
        for (int e = 0; e < 8; ++e) cv.u[e] = 0x3F80;  // bf16 1.0
        ones = cv.b;
    }

    // stage K and V^T tiles for kv0 into buffer `buf`.
    // LDS linear; global source pre-swizzled: 16B-unit u -> u ^ ((u>>3)&7)
    auto STAGE = [&](int buf, int kv0) {
        int u = wid * 64 + lane;               // 0..511 : row=u>>3, unit=u&7
        int sw = (u ^ (u >> 3)) & 7;
        const unsigned short* gk = Kt + (size_t)kv0 * HDIM +
                                   (size_t)((u & ~7) | sw) * 8;
        __builtin_amdgcn_global_load_lds((gq_t*)gk,
            (lq_t*)(&Ks[buf][(wid * 64) * 8]), 16, 0, 0);
        const unsigned short* gv = Vb + (size_t)(u >> 3) * NSEQ + kv0 + sw * 8;
        __builtin_amdgcn_global_load_lds((gq_t*)gv,
            (lq_t*)(&Vs[buf][(wid * 64) * 8]), 16, 0, 0);
    };

    STAGE(0, 0);
    __syncthreads();  // barrier drain (vmcnt 0) -> tile 0 ready

    const int rx = (r & 7) << 3;
    const int c0 = (g * 8) ^ rx;          // swizzled col (16B units*8) for k-half 0
    const int c1 = (g * 8 + 32) ^ rx;     // and k-half 1

    int cur = 0;
    for (int kv0 = 0; kv0 < NSEQ; kv0 += 64) {
        STAGE(cur ^ 1, (kv0 + 64) & (NSEQ - 1));  // prefetch next (wraps, harmless)

        const unsigned short* kb = &Ks[cur][0];
        const unsigned short* vl = &Vs[cur][0];

        // S = Q K^T (log2-domain: Q pre-scaled). C: row q = g*4+rr, col kv = nf*16+r
        f32x4 s[4];
#pragma unroll
        for (int nf = 0; nf < 4; ++nf) {
            int ro = (nf * 16 + r) * 64;
            f32x4 a = zero;
            a = __builtin_amdgcn_mfma_f32_16x16x32_bf16(
                qf[0], *(const bf16x8*)(kb + ro + c0), a, 0, 0, 0);
            a = __builtin_amdgcn_mfma_f32_16x16x32_bf16(
                qf[1], *(const bf16x8*)(kb + ro + c1), a, 0, 0, 0);
            s[nf] = a;
        }

        // row max over the 64 kv: in-lane over nf, then over the 16 r-lanes
        float pm[4];
#pragma unroll
        for (int rr = 0; rr < 4; ++rr)
            pm[rr] = fmaxf(fmaxf(s[0][rr], s[1][rr]), fmaxf(s[2][rr], s[3][rr]));
#pragma unroll
        for (int msk = 1; msk <= 8; msk <<= 1)
#pragma unroll
            for (int rr = 0; rr < 4; ++rr)
                pm[rr] = fmaxf(pm[rr], __shfl_xor(pm[rr], msk, 64));

        float al[4];
#pragma unroll
        for (int rr = 0; rr < 4; ++rr) {
            float mn = fmaxf(mrow[rr], pm[rr]);
            al[rr] = exp2_fast(mrow[rr] - mn);
            mrow[rr] = mn;
        }
#pragma unroll
        for (int nf = 0; nf < 4; ++nf)
#pragma unroll
            for (int rr = 0; rr < 4; ++rr)
                s[nf][rr] = exp2_fast(s[nf][rr] - mrow[rr]);

        // rescale running O and l
#pragma unroll
        for (int df = 0; df < 4; ++df)
#pragma unroll
            for (int rr = 0; rr < 4; ++rr) oacc[df][rr] *= al[rr];
#pragma unroll
        for (int rr = 0; rr < 4; ++rr) lacc[rr] *= al[rr];

        // P: C-layout -> per-wave LDS [16 q][72] -> A-layout fragments
#pragma unroll
        for (int nf = 0; nf < 4; ++nf)
#pragma unroll
            for (int rr = 0; rr < 4; ++rr)
                Pw[(g * 4 + rr) * 72 + nf * 16 + r] = f2bf(s[nf][rr]);

        bf16x8 pa0 = *(const bf16x8*)(Pw + r * 72 + g * 8);
        bf16x8 pa1 = *(const bf16x8*)(Pw + r * 72 + 32 + g * 8);

        // l += rowsum(P) via MFMA with ones (C[q][*] = sum)
        lacc = __builtin_amdgcn_mfma_f32_16x16x32_bf16(pa0, ones, lacc, 0, 0, 0);
        lacc = __builtin_amdgcn_mfma_f32_16x16x32_bf16(pa1, ones, lacc, 0, 0, 0);

        // O += P V
#pragma unroll
        for (int df = 0; df < 4; ++df) {
            int ro = (df * 16 + r) * 64;
            oacc[df] = __builtin_amdgcn_mfma_f32_16x16x32_bf16(
                pa0, *(const bf16x8*)(vl + ro + c0), oacc[df], 0, 0, 0);
            oacc[df] = __builtin_amdgcn_mfma_f32_16x16x32_bf16(
                pa1, *(const bf16x8*)(vl + ro + c1), oacc[df], 0, 0, 0);
        }

        __syncthreads();  // drains prefetch vmcnt + protects buffers
        cur ^= 1;
    }

    // epilogue
    int row = b * NSEQ + qt * 128 + wid * 16 + g * 4;
#pragma unroll
    for (int rr = 0; rr < 4; ++rr) {
        float inv = 1.0f / lacc[rr];
#pragma unroll
        for (int df = 0; df < 4; ++df)
            AO[(size_t)(row + rr) * DDIM + h * HDIM + df * 16 + r] =
                f2bf(oacc[df][rr] * inv);
    }
}

// ---------------- host launch ----------------
extern "C" void kernel_launch(void* const* d_in, const int* in_sizes, int n_in,
                              void* d_out, int out_size, void* d_ws, size_t ws_size,
                              hipStream_t stream) {
    const float* q = (const float*)d_in[0];
    const float* k = (const float*)d_in[1];
    const float* v = (const float*)d_in[2];
    const float* Wq = (const float*)d_in[3];
    const float* bq = (const float*)d_in[4];
    const float* Wk = (const float*)d_in[5];
    const float* bk = (const float*)d_in[6];
    const float* Wv = (const float*)d_in[7];
    const float* bv = (const float*)d_in[8];
    const float* Wo = (const float*)d_in[9];
    const float* bo = (const float*)d_in[10];
    float* out = (float*)d_out;

    unsigned short* ws = (unsigned short*)d_ws;
    const size_t TOKD = (size_t)NTOK * DDIM;  // 4,194,304
    const size_t WD = (size_t)DDIM * DDIM;    // 1,048,576
    unsigned short* qb = ws;
    unsigned short* kb = qb + TOKD;
    unsigned short* vb = kb + TOKD;
    unsigned short* Wqb = vb + TOKD;
    unsigned short* Wkb = Wqb + WD;
    unsigned short* Wvb = Wkb + WD;
    unsigned short* Wob = Wvb + WD;
    unsigned short* Qp = Wob + WD;
    unsigned short* Kp = Qp + TOKD;   // head-major K
    unsigned short* Vp = Kp + TOKD;   // token-major V
    unsigned short* AOp = Vp + TOKD;
    unsigned short* Vtb = qb;  // reuse: qb is dead after gemm_qkv; V^T lives here

    const int tok8 = (int)(TOKD / 8);  // 524288
    const int w8 = (int)(WD / 8);      // 131072
    cvt3_kernel<<<dim3(tok8 / 256, 1, 3), 256, 0, stream>>>(q, k, v, qb, kb, vb);
    cvt4_kernel<<<dim3(w8 / 256, 1, 4), 256, 0, stream>>>(Wq, Wk, Wv, Wo,
                                                          Wqb, Wkb, Wvb, Wob);
    gemm_qkv_kernel<<<dim3(8, 32, 3), 256, 0, stream>>>(qb, kb, vb, Wqb, Wkb, Wvb,
                                                        bq, bk, bv, Qp, Kp, Vp);
    vtrans_kernel<<<dim3(32, 32), 256, 0, stream>>>(Vp, Vtb);
    attn_kernel<<<dim3(16, 32), 512, 0, stream>>>(Qp, Kp, Vtb, AOp);
    gemm_out_kernel<<<dim3(8, 32), 256, 0, stream>>>(AOp, Wob, bo, out);
}